// Round 12
// baseline (96.629 us; speedup 1.0000x reference)
//
#include <hip/hip_runtime.h>

typedef __attribute__((ext_vector_type(8))) short short8;
typedef __attribute__((ext_vector_type(4))) float f32x4;
typedef unsigned int u32;

#define SLOT_B 2176         // 4 rows * 34 w-chunks * 16 B (8 bf16 channels)
#define NSLOT 4
#define CSTRIDE 131072      // channel stride in x (elements): 32*64*64

__device__ __forceinline__ unsigned short f2bf(float f) {
  unsigned u = __builtin_bit_cast(unsigned, f);
  u += 0x7FFFu + ((u >> 16) & 1u);          // RNE (inputs finite)
  return (unsigned short)(u >> 16);
}
__device__ __forceinline__ u32 cvtpk(float lo, float hi) {
  u32 r;
  asm("v_cvt_pk_bf16_f32 %0, %1, %2" : "=v"(r) : "v"(lo), "v"(hi));
  return r;
}

#define MFMA1(A, B, C) __builtin_amdgcn_mfma_f32_16x16x32_bf16(A, B, C, 0, 0, 0)

// 18-MFMA group for w-tile WT from row-fragments F0..F3 (rows 0..3 of plane).
// K0: open gen dp (C=0); K1: gen dp-1 (kd=1); K2: gen dp-2 (kd=2).
#define MGRP(F0, F1, F2, F3, WT, AN, AM, AO, K0, K1, K2)                      \
  {                                                                           \
    if (K0) {                                                                 \
      AN[0][WT] = MFMA1(F0, bfragB[0][0], zf4);                               \
      AN[1][WT] = MFMA1(F1, bfragB[0][0], zf4);                               \
      AN[0][WT] = MFMA1(F1, bfragB[0][1], AN[0][WT]);                         \
      AN[1][WT] = MFMA1(F2, bfragB[0][1], AN[1][WT]);                         \
      AN[0][WT] = MFMA1(F2, bfragB[0][2], AN[0][WT]);                         \
      AN[1][WT] = MFMA1(F3, bfragB[0][2], AN[1][WT]);                         \
    }                                                                         \
    if (K1) {                                                                 \
      AM[0][WT] = MFMA1(F0, bfragB[1][0], AM[0][WT]);                         \
      AM[1][WT] = MFMA1(F1, bfragB[1][0], AM[1][WT]);                         \
      AM[0][WT] = MFMA1(F1, bfragB[1][1], AM[0][WT]);                         \
      AM[1][WT] = MFMA1(F2, bfragB[1][1], AM[1][WT]);                         \
      AM[0][WT] = MFMA1(F2, bfragB[1][2], AM[0][WT]);                         \
      AM[1][WT] = MFMA1(F3, bfragB[1][2], AM[1][WT]);                         \
    }                                                                         \
    if (K2) {                                                                 \
      AO[0][WT] = MFMA1(F0, bfragB[2][0], AO[0][WT]);                         \
      AO[1][WT] = MFMA1(F1, bfragB[2][0], AO[1][WT]);                         \
      AO[0][WT] = MFMA1(F1, bfragB[2][1], AO[0][WT]);                         \
      AO[1][WT] = MFMA1(F2, bfragB[2][1], AO[1][WT]);                         \
      AO[0][WT] = MFMA1(F2, bfragB[2][2], AO[0][WT]);                         \
      AO[1][WT] = MFMA1(F3, bfragB[2][2], AO[1][WT]);                         \
    }                                                                         \
  }

// Barrier-free PROC(dp): issue loads(dp+2) -> 36-MFMA burst on plane dp
// (slot dp&3) -> cvt+ds_write(dp+2) (loads a full burst old: latency hidden)
// -> pool-close gen dp-2. Wave-private LDS: slot (dp+2)&3 was read 2 PROCs
// ago in this wave's own program order (DS in-order; sched_barrier(0) blocks
// compiler hoisting). 3 decorrelated waves/SIMD tile the matrix pipe.
#define PROC(DP, AN, AM, AO, K0, K1, K2, CL, SV, ST)                          \
  {                                                                           \
    const int dp_ = (DP);                                                     \
    if (ST) {                                                                 \
      stage_load(dp_ + 2);                                                    \
      __builtin_amdgcn_sched_barrier(0);                                      \
    }                                                                         \
    const int sb_ = (dp_ & 3) * SLOT_B;                                       \
    __builtin_amdgcn_s_setprio(1);                                            \
    _Pragma("unroll") for (int wt = 0; wt < 2; ++wt) {                        \
      const short8 f0 = *(const short8*)(smem + sb_ + 0 * 544 + physoff[wt]); \
      const short8 f1 = *(const short8*)(smem + sb_ + 1 * 544 + physoff[wt]); \
      const short8 f2 = *(const short8*)(smem + sb_ + 2 * 544 + physoff[wt]); \
      const short8 f3 = *(const short8*)(smem + sb_ + 3 * 544 + physoff[wt]); \
      MGRP(f0, f1, f2, f3, wt, AN, AM, AO, K0, K1, K2);                       \
    }                                                                         \
    __builtin_amdgcn_s_setprio(0);                                            \
    __builtin_amdgcn_sched_barrier(0);                                        \
    if (ST) stage_write(dp_ + 2);                                             \
    if (CL) {                                                                 \
      _Pragma("unroll") for (int wt = 0; wt < 2; ++wt) {                      \
        const float e01 = fmaxf(fmaxf(AO[0][wt][0], AO[0][wt][1]),            \
                                fmaxf(AO[1][wt][0], AO[1][wt][1]));           \
        const float e23 = fmaxf(fmaxf(AO[0][wt][2], AO[0][wt][3]),            \
                                fmaxf(AO[1][wt][2], AO[1][wt][3]));           \
        if (SV) {                                                             \
          p01[wt] = e01; p23[wt] = e23;                                       \
        } else {                                                              \
          sum += fmaxf(p01[wt], e01);                                         \
          if (!(wt == 1 && wmask)) sum += fmaxf(p23[wt], e23);                \
        }                                                                     \
      }                                                                       \
    }                                                                         \
  }

// grid: 3968 = 64 b * 31 h'-pairs * 2 w-halves ; block: 64 (ONE wave)
__launch_bounds__(64, 3)
__global__ void conv_fused(const float* __restrict__ x,
                           const float* __restrict__ cw,
                           float* __restrict__ ws) {
  __shared__ __align__(16) unsigned char smem[NSLOT * SLOT_B + 16];

  // XCD-chunked bijective swizzle (3968 = 8*496): same-image blocks cluster
  // on one XCD -> h/w halo rows shared in that XCD's L2.
  const int rb  = blockIdx.x;
  const int bid = (rb & 7) * 496 + (rb >> 3);
  const int b   = bid / 62;
  const int r2  = bid - 62 * b;
  const int q   = r2 >> 1;           // h'-pair: outputs h' = 2q, 2q+1 (q<=30)
  const int wh  = r2 & 1;            // w-half: outputs w' in [32wh, 32wh+31]
  const int h0  = 2 * q;             // input rows h0..h0+3 (<= 63, no clamp)
  const int w0  = wh * 32;           // input w base

  const int lane = threadIdx.x;      // 0..63
  const int nm   = lane & 15;
  const int g    = lane >> 4;

  const float* xb = x + (size_t)b * (8u * 32u * 64u * 64u);  // SGPR base

  // ---- B fragments: 9 (kd,kh) weight-sets, K = kw*8 + c (24 used, 8 pad) ----
  short8 bfragB[3][3];
#pragma unroll
  for (int kd = 0; kd < 3; ++kd)
#pragma unroll
    for (int kh = 0; kh < 3; ++kh) {
      short8 f;
#pragma unroll
      for (int j = 0; j < 8; ++j) {
        float v = (g < 3) ? cw[(nm * 8 + j) * 27 + kd * 9 + kh * 3 + g] : 0.f;
        f[j] = (short)f2bf(v);
      }
      bfragB[kd][kh] = f;
    }

  // ---- A-fragment chunk offsets; lane nm = output column m = w' local ----
  const int gc = (g < 3) ? g : 2;     // pad lanes read real data, weight = 0
  int physoff[2];
#pragma unroll
  for (int wt = 0; wt < 2; ++wt) physoff[wt] = (wt * 16 + nm + gc) * 16;

  // ---- wave-private staging: 136 slots = 4 rows x 34 chunks; lane covers
  // slots lane, lane+64, lane+128(<136). w clamped at 63 (clamped chunks feed
  // only masked outputs w'=62,63).
  int st_toff[3], st_off[3];
#pragma unroll
  for (int pass = 0; pass < 3; ++pass) {
    const int s   = lane + pass * 64;
    const int row = (s < 136) ? (s / 34) : 0;
    const int ch  = (s < 136) ? (s - 34 * row) : 0;
    int w = w0 + ch; if (w > 63) w = 63;
    st_toff[pass] = (h0 + row) * 64 + w;       // element offset, ch 0, plane 0
    st_off[pass]  = row * 544 + ch * 16;
  }
  const bool act2 = (lane < 8);   // slots 128..135

  float ld[3][8];   // single in-flight staging buffer (24 VGPRs)

  auto stage_load = [&](int p) {
    const int pbase = p * 4096;
#pragma unroll
    for (int pass = 0; pass < 3; ++pass) {
      if (pass < 2 || act2) {
        const int o = st_toff[pass] + pbase;
#pragma unroll
        for (int c = 0; c < 8; ++c)
          ld[pass][c] = (xb + (size_t)c * CSTRIDE)[o];   // SGPR base + VGPR off
      }
    }
  };
  auto stage_write = [&](int p) {
    unsigned char* d = smem + (p & 3) * SLOT_B;
#pragma unroll
    for (int pass = 0; pass < 3; ++pass) {
      if (pass < 2 || act2) {
        uint4 v;
        v.x = cvtpk(ld[pass][0], ld[pass][1]);
        v.y = cvtpk(ld[pass][2], ld[pass][3]);
        v.z = cvtpk(ld[pass][4], ld[pass][5]);
        v.w = cvtpk(ld[pass][6], ld[pass][7]);
        *(uint4*)(d + st_off[pass]) = v;
      }
    }
  };

  // invalid outputs w' = 62,63: wh==1, wt==1, g==3, acc regs 2,3 (e23)
  const bool wmask = (wh == 1) && (g == 3);

  const f32x4 zf4 = {0.f, 0.f, 0.f, 0.f};
  float sum = 0.f;
  float p01[2], p23[2];
  f32x4 accA[2][2], accB[2][2], accC[2][2];    // gen % 3 rotation

  // prologue: planes 0,1 staged; no barrier (wave-private data)
  stage_load(0); stage_write(0);
  stage_load(1); stage_write(1);

  //            AN    AM    AO    K0 K1 K2 CL SV ST
  PROC(0, accA, accB, accC, 1, 0, 0, 0, 0, 1)   // stage 2
  PROC(1, accB, accA, accC, 1, 1, 0, 0, 0, 1)   // stage 3

  // main: dp = 2..25, closures d' = 0..23 (even=save, odd=combine)
  for (int p0 = 2; p0 <= 20; p0 += 6) {
    PROC(p0 + 0, accC, accB, accA, 1, 1, 1, 1, 1, 1)
    PROC(p0 + 1, accA, accC, accB, 1, 1, 1, 1, 0, 1)
    PROC(p0 + 2, accB, accA, accC, 1, 1, 1, 1, 1, 1)
    PROC(p0 + 3, accC, accB, accA, 1, 1, 1, 1, 0, 1)
    PROC(p0 + 4, accA, accC, accB, 1, 1, 1, 1, 1, 1)
    PROC(p0 + 5, accB, accA, accC, 1, 1, 1, 1, 0, 1)
  }
  // epilogue: dp = 26..31 (last stage: plane 31 at PROC(29); gens 30,31 skipped)
  PROC(26, accC, accB, accA, 1, 1, 1, 1, 1, 1)
  PROC(27, accA, accC, accB, 1, 1, 1, 1, 0, 1)
  PROC(28, accB, accA, accC, 1, 1, 1, 1, 1, 1)
  PROC(29, accC, accB, accA, 1, 1, 1, 1, 0, 1)
  PROC(30, accA, accC, accB, 0, 1, 1, 1, 1, 0)
  PROC(31, accB, accA, accC, 0, 0, 1, 1, 0, 0)

  // wave reduce -> one partial per wave-tile (stored by LOGICAL bid)
#pragma unroll
  for (int off = 32; off > 0; off >>= 1) sum += __shfl_down(sum, off);
  if (lane == 0) ws[bid] = sum;
}

// out[b] = 0.5 * S_b / 14415 + 0.5 * sum(conv_bias) + sum(bias)
__global__ void finalize_k(const float* __restrict__ ws,
                           const float* __restrict__ cb,
                           const float* __restrict__ bias,
                           float* __restrict__ out) {
  const int b = threadIdx.x;
  float s = 0.f;
#pragma unroll
  for (int i = 0; i < 62; ++i) s += ws[b * 62 + i];
  float cbs = 0.f, bs = 0.f;
#pragma unroll
  for (int c = 0; c < 16; ++c) { cbs += cb[c]; bs += bias[c]; }
  out[b] = 0.5f * s / 14415.f + 0.5f * cbs + bs;
}

extern "C" void kernel_launch(void* const* d_in, const int* in_sizes, int n_in,
                              void* d_out, int out_size, void* d_ws, size_t ws_size,
                              hipStream_t stream) {
  const float* x    = (const float*)d_in[0];
  const float* cw   = (const float*)d_in[1];
  const float* cb   = (const float*)d_in[2];
  const float* bias = (const float*)d_in[3];
  float* out = (float*)d_out;
  float* ws  = (float*)d_ws;   // 3968 floats

  hipLaunchKernelGGL(conv_fused, dim3(3968), dim3(64), 0, stream, x, cw, ws);
  hipLaunchKernelGGL(finalize_k, dim3(1), dim3(64), 0, stream, ws, cb, bias, out);
}